// Round 8
// baseline (229.719 us; speedup 1.0000x reference)
//
#include <hip/hip_runtime.h>

// Problem dims
#define Bn 2048
#define En 256
#define INn 2
#define Cn 100
#define D1n 20
#define D2n 20
#define On 100
#define H1n 128
#define H2n 64
#define Zn 20

// Inputs f32 (R1: bf16-read => NaN storm proves f32 memory; npz size 4.98MB ~= 5.39MB raw f32).
// Outputs f32 (harness doc: output dtype = reference output dtype = f32; out_npz 4.185MB ~= 4.52MB raw f32;
// R4/R6 identical-wrong-answer signature = bf16 ushorts packed into an f32 buffer).
// Comparator rounds ref to bf16 (hard-coded "(bf16, ref=np)" label, threshold = 2% of bf16(max|ref|)).

__device__ __forceinline__ float tanh_fast(float t) {
    float at = fabsf(t);
    float e  = exp2f(-2.885390082f * at);           // exp(-2|t|)
    float r  = (1.0f - e) * __builtin_amdgcn_rcpf(1.0f + e);
    return t < 0.0f ? -r : r;
}

// ONE kernel, one block (256 thr) per sample b; thread t owns position e=t.
// Block computes its own sample's VAE in LDS (no workspace, no 2nd kernel),
// then phi_x directly per the reference (no algebraic folds).
__global__ __launch_bounds__(256) void pivae_fused(
    const float* __restrict__ x,      const float* __restrict__ eps,
    const float* __restrict__ alpha_p,const float* __restrict__ centers,
    const float* __restrict__ W1,     const float* __restrict__ b1,
    const float* __restrict__ W2,     const float* __restrict__ b2,
    const float* __restrict__ W3,     const float* __restrict__ b3,
    const float* __restrict__ beta_W, const float* __restrict__ beta_b,
    const float* __restrict__ eW1,    const float* __restrict__ eb1,
    const float* __restrict__ eW2,    const float* __restrict__ eb2,
    const float* __restrict__ Wmu,    const float* __restrict__ bmu,
    const float* __restrict__ Wlv,    const float* __restrict__ blv,
    const float* __restrict__ dW1,    const float* __restrict__ db1,
    const float* __restrict__ dW2,    const float* __restrict__ db2,
    const float* __restrict__ dW3,    const float* __restrict__ db3,
    float* __restrict__ out_y1, float* __restrict__ out_y2,
    float* __restrict__ out_mu, float* __restrict__ out_lv)
{
    const int b = blockIdx.x;
    const int t = threadIdx.x;

    __shared__ __align__(16) float c0l[Cn];
    __shared__ __align__(16) float c1l[Cn];
    __shared__ __align__(16) float w1l[Cn * D1n];
    __shared__ __align__(16) float w2l[D1n * D2n];
    __shared__ __align__(16) float w3l[D2n * On];
    __shared__ __align__(16) float b1l[D1n];
    __shared__ __align__(16) float b2l[D2n];
    __shared__ __align__(16) float b3l[On];
    __shared__ __align__(16) float bwl[On];   // beta_W row for sample b
    __shared__ __align__(16) float rcl[On];   // recon row for sample b
    __shared__ float he1[H1n];
    __shared__ float he2[H2n];
    __shared__ float zz[Zn];
    __shared__ float hd1[H2n];
    __shared__ float hd2[H1n];

    // ---------------- stage shared weights / per-sample rows ----------------
    if (t < Cn) {
        const float2 cv = *reinterpret_cast<const float2*>(centers + 2 * t);
        c0l[t] = cv.x;
        c1l[t] = cv.y;
        bwl[t] = beta_W[b * On + t];
        b3l[t] = b3[t];
    }
    for (int i = t; i < Cn * D1n; i += 256) w1l[i] = W1[i];
    for (int i = t; i < D2n * On;  i += 256) w3l[i] = W3[i];
    for (int i = t; i < D1n * D2n; i += 256) w2l[i] = W2[i];
    if (t < D1n) b1l[t] = b1[t];
    if (t >= 64 && t < 64 + D2n) b2l[t - 64] = b2[t - 64];
    __syncthreads();

    // ---------------- VAE for sample b (in-block) ----------------
    // he1 = relu(beta @ eW1 + eb1)        (100 -> 128)
    if (t < H1n) {
        float a = eb1[t];
        #pragma unroll 4
        for (int i = 0; i < Cn; ++i) a += bwl[i] * eW1[i * H1n + t];
        he1[t] = fmaxf(a, 0.0f);
    }
    __syncthreads();
    // he2 = relu(he1 @ eW2 + eb2)         (128 -> 64)
    if (t < H2n) {
        float a = eb2[t];
        #pragma unroll 4
        for (int i = 0; i < H1n; ++i) a += he1[i] * eW2[i * H2n + t];
        he2[t] = fmaxf(a, 0.0f);
    }
    __syncthreads();
    // mu / logvar / z                     (64 -> 20)
    if (t < Zn) {
        float m = bmu[t], l = blv[t];
        #pragma unroll 4
        for (int i = 0; i < H2n; ++i) {
            float h = he2[i];
            m += h * Wmu[i * Zn + t];
            l += h * Wlv[i * Zn + t];
        }
        out_mu[b * Zn + t] = m;
        out_lv[b * Zn + t] = l;
        zz[t] = m + exp2f(0.72134752f * l) * eps[b * Zn + t];
    }
    __syncthreads();
    // hd1 = relu(z @ dW1 + db1)           (20 -> 64)
    if (t < H2n) {
        float a = db1[t];
        #pragma unroll
        for (int i = 0; i < Zn; ++i) a += zz[i] * dW1[i * H2n + t];
        hd1[t] = fmaxf(a, 0.0f);
    }
    __syncthreads();
    // hd2 = relu(hd1 @ dW2 + db2)         (64 -> 128)
    if (t < H1n) {
        float a = db2[t];
        #pragma unroll 4
        for (int i = 0; i < H2n; ++i) a += hd1[i] * dW2[i * H1n + t];
        hd2[t] = fmaxf(a, 0.0f);
    }
    __syncthreads();
    // recon = hd2 @ dW3 + db3             (128 -> 100)
    if (t < On) {
        float a = db3[t];
        #pragma unroll 4
        for (int i = 0; i < H1n; ++i) a += hd2[i] * dW3[i * On + t];
        rcl[t] = a;
    }
    __syncthreads();

    // ---------------- PHI for (b, e=t) ----------------
    const float2 xv = *reinterpret_cast<const float2*>(x + ((size_t)b * En + t) * 2);
    const float na  = -alpha_p[0] * 1.44269504f;   // exp(-a*d2) = exp2(na*d2)

    // h = feat @ W1   (accumulate, bias+tanh after)
    float h[D1n];
    #pragma unroll
    for (int j = 0; j < D1n; ++j) h[j] = 0.0f;
    for (int c = 0; c < Cn; ++c) {
        const float dx0 = xv.x - c0l[c];
        const float dx1 = xv.y - c1l[c];
        const float f = exp2f(na * (dx0 * dx0 + dx1 * dx1));
        const float4* wr = reinterpret_cast<const float4*>(&w1l[c * D1n]);
        #pragma unroll
        for (int q = 0; q < 5; ++q) {
            const float4 v = wr[q];
            h[4 * q + 0] = fmaf(f, v.x, h[4 * q + 0]);
            h[4 * q + 1] = fmaf(f, v.y, h[4 * q + 1]);
            h[4 * q + 2] = fmaf(f, v.z, h[4 * q + 2]);
            h[4 * q + 3] = fmaf(f, v.w, h[4 * q + 3]);
        }
    }
    #pragma unroll
    for (int j = 0; j < D1n; ++j) h[j] = tanh_fast(h[j] + b1l[j]);

    // g = tanh(h @ W2 + b2)
    float g[D2n];
    #pragma unroll
    for (int j = 0; j < D2n; ++j) g[j] = b2l[j];
    #pragma unroll
    for (int k = 0; k < D1n; ++k) {
        const float hk = h[k];
        const float4* wr = reinterpret_cast<const float4*>(&w2l[k * D2n]);
        #pragma unroll
        for (int q = 0; q < 5; ++q) {
            const float4 v = wr[q];
            g[4 * q + 0] = fmaf(hk, v.x, g[4 * q + 0]);
            g[4 * q + 1] = fmaf(hk, v.y, g[4 * q + 1]);
            g[4 * q + 2] = fmaf(hk, v.z, g[4 * q + 2]);
            g[4 * q + 3] = fmaf(hk, v.w, g[4 * q + 3]);
        }
    }
    #pragma unroll
    for (int j = 0; j < D2n; ++j) g[j] = tanh_fast(g[j]);

    // phi_x[o] = g @ W3 + b3 computed directly; dot with beta_W and recon.
    const float bb = beta_b[b];
    float y1 = bb, y2 = bb;
    for (int o4 = 0; o4 < On / 4; ++o4) {
        float4 p = *reinterpret_cast<const float4*>(&b3l[o4 * 4]);
        #pragma unroll
        for (int k = 0; k < D2n; ++k) {
            const float gk = g[k];
            const float4 wv = *reinterpret_cast<const float4*>(&w3l[k * On + o4 * 4]);
            p.x = fmaf(gk, wv.x, p.x);
            p.y = fmaf(gk, wv.y, p.y);
            p.z = fmaf(gk, wv.z, p.z);
            p.w = fmaf(gk, wv.w, p.w);
        }
        const float4 bw = *reinterpret_cast<const float4*>(&bwl[o4 * 4]);
        const float4 rc = *reinterpret_cast<const float4*>(&rcl[o4 * 4]);
        y1 += p.x * bw.x + p.y * bw.y + p.z * bw.z + p.w * bw.w;
        y2 += p.x * rc.x + p.y * rc.y + p.z * rc.z + p.w * rc.w;
    }

    const size_t oidx = (size_t)b * En + t;
    out_y1[oidx] = y1;
    out_y2[oidx] = y2;
}

extern "C" void kernel_launch(void* const* d_in, const int* in_sizes, int n_in,
                              void* d_out, int out_size, void* d_ws, size_t ws_size,
                              hipStream_t stream)
{
    const float* x       = (const float*)d_in[0];
    const float* eps     = (const float*)d_in[1];
    const float* alpha   = (const float*)d_in[2];
    const float* centers = (const float*)d_in[3];
    const float* W1      = (const float*)d_in[4];
    const float* b1      = (const float*)d_in[5];
    const float* W2      = (const float*)d_in[6];
    const float* b2      = (const float*)d_in[7];
    const float* W3      = (const float*)d_in[8];
    const float* b3      = (const float*)d_in[9];
    const float* beta_W  = (const float*)d_in[10];
    const float* beta_b  = (const float*)d_in[11];
    const float* eW1     = (const float*)d_in[12];
    const float* eb1     = (const float*)d_in[13];
    const float* eW2     = (const float*)d_in[14];
    const float* eb2     = (const float*)d_in[15];
    const float* Wmu     = (const float*)d_in[16];
    const float* bmu     = (const float*)d_in[17];
    const float* Wlv     = (const float*)d_in[18];
    const float* blv     = (const float*)d_in[19];
    const float* dW1     = (const float*)d_in[20];
    const float* db1     = (const float*)d_in[21];
    const float* dW2     = (const float*)d_in[22];
    const float* db2     = (const float*)d_in[23];
    const float* dW3     = (const float*)d_in[24];
    const float* db3     = (const float*)d_in[25];

    float* out    = (float*)d_out;
    float* out_y1 = out;                                  // (B,E)
    float* out_y2 = out + (size_t)Bn * En;                // (B,E)
    float* out_mu = out + (size_t)2 * Bn * En;            // (B,Z)
    float* out_lv = out_mu + (size_t)Bn * Zn;             // (B,Z)

    pivae_fused<<<dim3(Bn), dim3(256), 0, stream>>>(
        x, eps, alpha, centers, W1, b1, W2, b2, W3, b3, beta_W, beta_b,
        eW1, eb1, eW2, eb2, Wmu, bmu, Wlv, blv,
        dW1, db1, dW2, db2, dW3, db3,
        out_y1, out_y2, out_mu, out_lv);
}

// Round 13
// 200.890 us; speedup vs baseline: 1.1435x; 1.1435x over previous
//
#include <hip/hip_runtime.h>

// Problem dims
#define Bn 2048
#define En 256
#define INn 2
#define Cn 100
#define D1n 20
#define D2n 20
#define On 100
#define H1n 128
#define H2n 64
#define Zn 20

// Inputs f32, outputs f32 (verified green in R8).

__device__ __forceinline__ float tanh_fast(float t) {
    float at = fabsf(t);
    float e  = exp2f(-2.885390082f * at);           // exp(-2|t|)
    float r  = (1.0f - e) * __builtin_amdgcn_rcpf(1.0f + e);
    return t < 0.0f ? -r : r;
}

// One block (256 thr) per 2 samples (grid = B/2). Thread t: sample s = t>>7,
// positions e0=(t&127)*2 and e0+1. VAE for both samples computed in-block
// (each phase uses both halves of the block). W3 folded: y = g·u + s12.
__global__ __launch_bounds__(256) void pivae_fused2(
    const float* __restrict__ x,      const float* __restrict__ eps,
    const float* __restrict__ alpha_p,const float* __restrict__ centers,
    const float* __restrict__ W1,     const float* __restrict__ b1,
    const float* __restrict__ W2,     const float* __restrict__ b2,
    const float* __restrict__ W3,     const float* __restrict__ b3,
    const float* __restrict__ beta_W, const float* __restrict__ beta_b,
    const float* __restrict__ eW1,    const float* __restrict__ eb1,
    const float* __restrict__ eW2,    const float* __restrict__ eb2,
    const float* __restrict__ Wmu,    const float* __restrict__ bmu,
    const float* __restrict__ Wlv,    const float* __restrict__ blv,
    const float* __restrict__ dW1,    const float* __restrict__ db1,
    const float* __restrict__ dW2,    const float* __restrict__ db2,
    const float* __restrict__ dW3,    const float* __restrict__ db3,
    float* __restrict__ out_y1, float* __restrict__ out_y2,
    float* __restrict__ out_mu, float* __restrict__ out_lv)
{
    const int t  = threadIdx.x;
    const int b0 = blockIdx.x * 2;

    __shared__ __align__(16) float  w1l[Cn * D1n];
    __shared__ __align__(16) float  w2l[D1n * D2n];
    __shared__ __align__(16) float4 ctr[Cn];        // {cs0, cs1, nr2c, 0}
    __shared__ __align__(16) float  b1l[D1n];
    __shared__ __align__(16) float  b2l[D2n];
    __shared__ __align__(16) float  bwl[2][On];
    __shared__ __align__(16) float  rcl[2][On];
    __shared__ float he1[2][H1n];
    __shared__ float he2[2][H2n];
    __shared__ float zzs[2][Zn];
    __shared__ float hd1[2][H2n];
    __shared__ float hd2[2][H1n];
    __shared__ float u1l[2][Zn];
    __shared__ float u2l[2][Zn];
    __shared__ float s12[2][2];

    const float na = -alpha_p[0] * 1.44269504f;     // exp(-a*d2) = exp2(na*d2)

    // ---------------- stage ----------------
    if (t < Cn) {
        const float2 cv = *reinterpret_cast<const float2*>(centers + 2 * t);
        ctr[t] = make_float4(-2.0f * na * cv.x, -2.0f * na * cv.y,
                             na * (cv.x * cv.x + cv.y * cv.y), 0.0f);
    }
    for (int i = t; i < Cn * D1n; i += 256) w1l[i] = W1[i];
    for (int i = t; i < D1n * D2n; i += 256) w2l[i] = W2[i];
    if (t < D1n) b1l[t] = b1[t];
    if (t >= 32 && t < 32 + D2n) b2l[t - 32] = b2[t - 32];
    if (t < 2 * On) { int s = t / On, o = t - s * On; bwl[s][o] = beta_W[(b0 + s) * On + o]; }
    __syncthreads();

    // ---------------- VAE (both samples) ----------------
    // he1 = relu(beta @ eW1 + eb1)      (100->128), 256 threads
    {
        const int s = t >> 7, j = t & 127;
        float a = eb1[j];
        #pragma unroll 4
        for (int i = 0; i < Cn; ++i) a += bwl[s][i] * eW1[i * H1n + j];
        he1[s][j] = fmaxf(a, 0.0f);
    }
    __syncthreads();
    // he2 = relu(he1 @ eW2 + eb2)       (128->64), 128 threads
    if (t < 128) {
        const int s = t >> 6, j = t & 63;
        float a = eb2[j];
        #pragma unroll 4
        for (int i = 0; i < H1n; ++i) a += he1[s][i] * eW2[i * H2n + j];
        he2[s][j] = fmaxf(a, 0.0f);
    }
    __syncthreads();
    // mu / logvar / z                   (64->20), 2x20 of 64 threads
    if (t < 64) {
        const int s = t >> 5, j = t & 31;
        if (j < Zn) {
            float m = bmu[j], l = blv[j];
            #pragma unroll 4
            for (int i = 0; i < H2n; ++i) {
                const float h = he2[s][i];
                m += h * Wmu[i * Zn + j];
                l += h * Wlv[i * Zn + j];
            }
            out_mu[(b0 + s) * Zn + j] = m;
            out_lv[(b0 + s) * Zn + j] = l;
            zzs[s][j] = m + exp2f(0.72134752f * l) * eps[(b0 + s) * Zn + j];
        }
    }
    __syncthreads();
    // hd1 = relu(z @ dW1 + db1)         (20->64), 128 threads
    if (t < 128) {
        const int s = t >> 6, j = t & 63;
        float a = db1[j];
        #pragma unroll
        for (int i = 0; i < Zn; ++i) a += zzs[s][i] * dW1[i * H2n + j];
        hd1[s][j] = fmaxf(a, 0.0f);
    }
    __syncthreads();
    // hd2 = relu(hd1 @ dW2 + db2)       (64->128), 256 threads
    {
        const int s = t >> 7, j = t & 127;
        float a = db2[j];
        #pragma unroll 4
        for (int i = 0; i < H2n; ++i) a += hd1[s][i] * dW2[i * H1n + j];
        hd2[s][j] = fmaxf(a, 0.0f);
    }
    __syncthreads();
    // recon = hd2 @ dW3 + db3           (128->100), 200 threads
    if (t < 2 * On) {
        const int s = t / On, o = t - s * On;
        float a = db3[o];
        #pragma unroll 4
        for (int i = 0; i < H1n; ++i) a += hd2[s][i] * dW3[i * On + o];
        rcl[s][o] = a;
    }
    __syncthreads();
    // u1[k]=W3[k,:]@beta, u2[k]=W3[k,:]@recon (80 thr); s1,s2 (4 thr)
    if (t < 80) {
        const int s = t / 40, r = t - 40 * s, which = r / 20, k = r - 20 * which;
        const float* src = which ? rcl[s] : bwl[s];
        float a = 0.0f;
        #pragma unroll 4
        for (int o = 0; o < On; ++o) a += W3[k * On + o] * src[o];
        float (*dst)[Zn] = which ? u2l : u1l;
        dst[s][k] = a;
    } else if (t < 84) {
        const int idx = t - 80, s = idx >> 1, which = idx & 1;
        const float* src = which ? rcl[s] : bwl[s];
        float a = beta_b[b0 + s];
        #pragma unroll 4
        for (int o = 0; o < On; ++o) a += b3[o] * src[o];
        s12[s][which] = a;
    }
    __syncthreads();

    // ---------------- PHI: sample s, positions e0, e0+1 ----------------
    const int s  = t >> 7;
    const int e0 = (t & 127) * 2;
    const float4 xv = *reinterpret_cast<const float4*>(x + ((size_t)(b0 + s) * En + e0) * INn);
    const float A0 = na * (xv.x * xv.x + xv.y * xv.y);
    const float A1 = na * (xv.z * xv.z + xv.w * xv.w);

    float h0[D1n], h1[D1n];
    #pragma unroll
    for (int j = 0; j < D1n; ++j) { h0[j] = 0.0f; h1[j] = 0.0f; }

    for (int c = 0; c < Cn; ++c) {
        const float4 cc = ctr[c];
        const float arg0 = fmaf(xv.x, cc.x, fmaf(xv.y, cc.y, A0 + cc.z));
        const float arg1 = fmaf(xv.z, cc.x, fmaf(xv.w, cc.y, A1 + cc.z));
        const float f0 = exp2f(arg0);
        const float f1 = exp2f(arg1);
        const float4* wr = reinterpret_cast<const float4*>(&w1l[c * D1n]);
        #pragma unroll
        for (int q = 0; q < 5; ++q) {
            const float4 v = wr[q];
            h0[4*q+0] = fmaf(f0, v.x, h0[4*q+0]);  h1[4*q+0] = fmaf(f1, v.x, h1[4*q+0]);
            h0[4*q+1] = fmaf(f0, v.y, h0[4*q+1]);  h1[4*q+1] = fmaf(f1, v.y, h1[4*q+1]);
            h0[4*q+2] = fmaf(f0, v.z, h0[4*q+2]);  h1[4*q+2] = fmaf(f1, v.z, h1[4*q+2]);
            h0[4*q+3] = fmaf(f0, v.w, h0[4*q+3]);  h1[4*q+3] = fmaf(f1, v.w, h1[4*q+3]);
        }
    }
    #pragma unroll
    for (int j = 0; j < D1n; ++j) {
        h0[j] = tanh_fast(h0[j] + b1l[j]);
        h1[j] = tanh_fast(h1[j] + b1l[j]);
    }

    // g = tanh(h @ W2 + b2), both positions sharing each W2 row read
    float g0[D2n], g1[D2n];
    #pragma unroll
    for (int j = 0; j < D2n; ++j) { g0[j] = b2l[j]; g1[j] = b2l[j]; }
    #pragma unroll
    for (int k = 0; k < D1n; ++k) {
        const float hk0 = h0[k], hk1 = h1[k];
        const float4* wr = reinterpret_cast<const float4*>(&w2l[k * D2n]);
        #pragma unroll
        for (int q = 0; q < 5; ++q) {
            const float4 v = wr[q];
            g0[4*q+0] = fmaf(hk0, v.x, g0[4*q+0]);  g1[4*q+0] = fmaf(hk1, v.x, g1[4*q+0]);
            g0[4*q+1] = fmaf(hk0, v.y, g0[4*q+1]);  g1[4*q+1] = fmaf(hk1, v.y, g1[4*q+1]);
            g0[4*q+2] = fmaf(hk0, v.z, g0[4*q+2]);  g1[4*q+2] = fmaf(hk1, v.z, g1[4*q+2]);
            g0[4*q+3] = fmaf(hk0, v.w, g0[4*q+3]);  g1[4*q+3] = fmaf(hk1, v.w, g1[4*q+3]);
        }
    }

    // y = s12 + g . u   (W3/b3 folded)
    float y1_0 = s12[s][0], y1_1 = s12[s][0];
    float y2_0 = s12[s][1], y2_1 = s12[s][1];
    #pragma unroll
    for (int k = 0; k < D2n; ++k) {
        const float gk0 = tanh_fast(g0[k]);
        const float gk1 = tanh_fast(g1[k]);
        const float uk1 = u1l[s][k], uk2 = u2l[s][k];
        y1_0 = fmaf(gk0, uk1, y1_0);  y1_1 = fmaf(gk1, uk1, y1_1);
        y2_0 = fmaf(gk0, uk2, y2_0);  y2_1 = fmaf(gk1, uk2, y2_1);
    }

    const size_t oidx = (size_t)(b0 + s) * En + e0;
    *reinterpret_cast<float2*>(out_y1 + oidx) = make_float2(y1_0, y1_1);
    *reinterpret_cast<float2*>(out_y2 + oidx) = make_float2(y2_0, y2_1);
}

extern "C" void kernel_launch(void* const* d_in, const int* in_sizes, int n_in,
                              void* d_out, int out_size, void* d_ws, size_t ws_size,
                              hipStream_t stream)
{
    const float* x       = (const float*)d_in[0];
    const float* eps     = (const float*)d_in[1];
    const float* alpha   = (const float*)d_in[2];
    const float* centers = (const float*)d_in[3];
    const float* W1      = (const float*)d_in[4];
    const float* b1      = (const float*)d_in[5];
    const float* W2      = (const float*)d_in[6];
    const float* b2      = (const float*)d_in[7];
    const float* W3      = (const float*)d_in[8];
    const float* b3      = (const float*)d_in[9];
    const float* beta_W  = (const float*)d_in[10];
    const float* beta_b  = (const float*)d_in[11];
    const float* eW1     = (const float*)d_in[12];
    const float* eb1     = (const float*)d_in[13];
    const float* eW2     = (const float*)d_in[14];
    const float* eb2     = (const float*)d_in[15];
    const float* Wmu     = (const float*)d_in[16];
    const float* bmu     = (const float*)d_in[17];
    const float* Wlv     = (const float*)d_in[18];
    const float* blv     = (const float*)d_in[19];
    const float* dW1     = (const float*)d_in[20];
    const float* db1     = (const float*)d_in[21];
    const float* dW2     = (const float*)d_in[22];
    const float* db2     = (const float*)d_in[23];
    const float* dW3     = (const float*)d_in[24];
    const float* db3     = (const float*)d_in[25];

    float* out    = (float*)d_out;
    float* out_y1 = out;                                  // (B,E)
    float* out_y2 = out + (size_t)Bn * En;                // (B,E)
    float* out_mu = out + (size_t)2 * Bn * En;            // (B,Z)
    float* out_lv = out_mu + (size_t)Bn * Zn;             // (B,Z)

    pivae_fused2<<<dim3(Bn / 2), dim3(256), 0, stream>>>(
        x, eps, alpha, centers, W1, b1, W2, b2, W3, b3, beta_W, beta_b,
        eW1, eb1, eW2, eb2, Wmu, bmu, Wlv, blv,
        dW1, db1, dW2, db2, dW3, db3,
        out_y1, out_y2, out_mu, out_lv);
}

// Round 18
// 197.741 us; speedup vs baseline: 1.1617x; 1.0159x over previous
//
#include <hip/hip_runtime.h>

// Problem dims
#define Bn 2048
#define En 256
#define INn 2
#define Cn 100
#define D1n 20
#define D2n 20
#define On 100
#define H1n 128
#define H2n 64
#define Zn 20

// Inputs f32, outputs f32 (verified green in R8/R13).
// R13 lesson: wave-uniform weight rows in LDS = 16 waves/CU hammering one DS
// pipe (6 b128/wave/center). This round: W1/W2/centers/b1/b2 read via the
// scalar/const-cache path (uniform global loads); LDS only for cross-thread
// VAE state.

__device__ __forceinline__ float tanh_fast(float t) {
    float at = fabsf(t);
    float e  = exp2f(-2.885390082f * at);           // exp(-2|t|)
    float r  = (1.0f - e) * __builtin_amdgcn_rcpf(1.0f + e);
    return t < 0.0f ? -r : r;
}

// One block (256 thr) per 2 samples (grid = B/2). Thread t: sample s = t>>7,
// positions e0=(t&127)*2 and e0+1. VAE in-block; W3 folded: y = g·u + s12.
__global__ __launch_bounds__(256) void pivae_fused3(
    const float* __restrict__ x,      const float* __restrict__ eps,
    const float* __restrict__ alpha_p,const float* __restrict__ centers,
    const float* __restrict__ W1,     const float* __restrict__ b1,
    const float* __restrict__ W2,     const float* __restrict__ b2,
    const float* __restrict__ W3,     const float* __restrict__ b3,
    const float* __restrict__ beta_W, const float* __restrict__ beta_b,
    const float* __restrict__ eW1,    const float* __restrict__ eb1,
    const float* __restrict__ eW2,    const float* __restrict__ eb2,
    const float* __restrict__ Wmu,    const float* __restrict__ bmu,
    const float* __restrict__ Wlv,    const float* __restrict__ blv,
    const float* __restrict__ dW1,    const float* __restrict__ db1,
    const float* __restrict__ dW2,    const float* __restrict__ db2,
    const float* __restrict__ dW3,    const float* __restrict__ db3,
    float* __restrict__ out_y1, float* __restrict__ out_y2,
    float* __restrict__ out_mu, float* __restrict__ out_lv)
{
    const int t  = threadIdx.x;
    const int b0 = blockIdx.x * 2;

    __shared__ __align__(16) float bwl[2][On];   // beta_W rows
    __shared__ __align__(16) float rcl[2][On];   // recon rows
    __shared__ float he1[2][H1n];
    __shared__ float he2[2][H2n];
    __shared__ float zzs[2][Zn];
    __shared__ float hd1[2][H2n];
    __shared__ float hd2[2][H1n];
    __shared__ float u1l[2][Zn];
    __shared__ float u2l[2][Zn];
    __shared__ float s12[2][2];

    const float na = -alpha_p[0] * 1.44269504f;  // exp(-a*d2) = exp2(na*d2)

    // ---------------- stage per-sample rows only ----------------
    if (t < 2 * On) { int s = t / On, o = t - s * On; bwl[s][o] = beta_W[(b0 + s) * On + o]; }
    __syncthreads();

    // ---------------- VAE (both samples) ----------------
    // he1 = relu(beta @ eW1 + eb1)      (100->128), 256 threads
    {
        const int s = t >> 7, j = t & 127;
        float a = eb1[j];
        #pragma unroll 4
        for (int i = 0; i < Cn; ++i) a += bwl[s][i] * eW1[i * H1n + j];
        he1[s][j] = fmaxf(a, 0.0f);
    }
    __syncthreads();
    // he2 = relu(he1 @ eW2 + eb2)       (128->64), 128 threads
    if (t < 128) {
        const int s = t >> 6, j = t & 63;
        float a = eb2[j];
        #pragma unroll 4
        for (int i = 0; i < H1n; ++i) a += he1[s][i] * eW2[i * H2n + j];
        he2[s][j] = fmaxf(a, 0.0f);
    }
    __syncthreads();
    // mu / logvar / z                   (64->20), 2x20 of 64 threads
    if (t < 64) {
        const int s = t >> 5, j = t & 31;
        if (j < Zn) {
            float m = bmu[j], l = blv[j];
            #pragma unroll 4
            for (int i = 0; i < H2n; ++i) {
                const float h = he2[s][i];
                m += h * Wmu[i * Zn + j];
                l += h * Wlv[i * Zn + j];
            }
            out_mu[(b0 + s) * Zn + j] = m;
            out_lv[(b0 + s) * Zn + j] = l;
            zzs[s][j] = m + exp2f(0.72134752f * l) * eps[(b0 + s) * Zn + j];
        }
    }
    __syncthreads();
    // hd1 = relu(z @ dW1 + db1)         (20->64), 128 threads
    if (t < 128) {
        const int s = t >> 6, j = t & 63;
        float a = db1[j];
        #pragma unroll
        for (int i = 0; i < Zn; ++i) a += zzs[s][i] * dW1[i * H2n + j];
        hd1[s][j] = fmaxf(a, 0.0f);
    }
    __syncthreads();
    // hd2 = relu(hd1 @ dW2 + db2)       (64->128), 256 threads
    {
        const int s = t >> 7, j = t & 127;
        float a = db2[j];
        #pragma unroll 4
        for (int i = 0; i < H2n; ++i) a += hd1[s][i] * dW2[i * H1n + j];
        hd2[s][j] = fmaxf(a, 0.0f);
    }
    __syncthreads();
    // recon = hd2 @ dW3 + db3           (128->100), 200 threads
    if (t < 2 * On) {
        const int s = t / On, o = t - s * On;
        float a = db3[o];
        #pragma unroll 4
        for (int i = 0; i < H1n; ++i) a += hd2[s][i] * dW3[i * On + o];
        rcl[s][o] = a;
    }
    __syncthreads();
    // u1[k]=W3[k,:]@beta, u2[k]=W3[k,:]@recon (80 thr); s1,s2 (4 thr)
    if (t < 80) {
        const int s = t / 40, r = t - 40 * s, which = r / 20, k = r - 20 * which;
        const float* src = which ? rcl[s] : bwl[s];
        float a = 0.0f;
        #pragma unroll 4
        for (int o = 0; o < On; ++o) a += W3[k * On + o] * src[o];
        float (*dst)[Zn] = which ? u2l : u1l;
        dst[s][k] = a;
    } else if (t < 84) {
        const int idx = t - 80, s = idx >> 1, which = idx & 1;
        const float* src = which ? rcl[s] : bwl[s];
        float a = beta_b[b0 + s];
        #pragma unroll 4
        for (int o = 0; o < On; ++o) a += b3[o] * src[o];
        s12[s][which] = a;
    }
    __syncthreads();

    // ---------------- PHI: sample s, positions e0, e0+1 ----------------
    const int s  = t >> 7;
    const int e0 = (t & 127) * 2;
    const float4 xv = *reinterpret_cast<const float4*>(x + ((size_t)(b0 + s) * En + e0) * INn);
    const float A0 = na * (xv.x * xv.x + xv.y * xv.y);
    const float A1 = na * (xv.z * xv.z + xv.w * xv.w);

    float h0[D1n], h1[D1n];
    #pragma unroll
    for (int j = 0; j < D1n; ++j) { h0[j] = 0.0f; h1[j] = 0.0f; }

    #pragma unroll 2
    for (int c = 0; c < Cn; ++c) {
        // uniform loads -> scalar/const-cache path, not the DS pipe
        const float2 cv = *reinterpret_cast<const float2*>(centers + 2 * c);
        const float cs0 = -2.0f * na * cv.x;
        const float cs1 = -2.0f * na * cv.y;
        const float c2  = na * (cv.x * cv.x + cv.y * cv.y);
        const float f0 = exp2f(fmaf(xv.x, cs0, fmaf(xv.y, cs1, A0 + c2)));
        const float f1 = exp2f(fmaf(xv.z, cs0, fmaf(xv.w, cs1, A1 + c2)));
        const float4* wr = reinterpret_cast<const float4*>(W1 + c * D1n);
        #pragma unroll
        for (int q = 0; q < 5; ++q) {
            const float4 v = wr[q];
            h0[4*q+0] = fmaf(f0, v.x, h0[4*q+0]);  h1[4*q+0] = fmaf(f1, v.x, h1[4*q+0]);
            h0[4*q+1] = fmaf(f0, v.y, h0[4*q+1]);  h1[4*q+1] = fmaf(f1, v.y, h1[4*q+1]);
            h0[4*q+2] = fmaf(f0, v.z, h0[4*q+2]);  h1[4*q+2] = fmaf(f1, v.z, h1[4*q+2]);
            h0[4*q+3] = fmaf(f0, v.w, h0[4*q+3]);  h1[4*q+3] = fmaf(f1, v.w, h1[4*q+3]);
        }
    }
    #pragma unroll
    for (int j = 0; j < D1n; ++j) {
        h0[j] = tanh_fast(h0[j] + b1[j]);
        h1[j] = tanh_fast(h1[j] + b1[j]);
    }

    // g = tanh(h @ W2 + b2), W2 rows via uniform loads
    float g0[D2n], g1[D2n];
    #pragma unroll
    for (int j = 0; j < D2n; ++j) { const float bj = b2[j]; g0[j] = bj; g1[j] = bj; }
    #pragma unroll
    for (int k = 0; k < D1n; ++k) {
        const float hk0 = h0[k], hk1 = h1[k];
        const float4* wr = reinterpret_cast<const float4*>(W2 + k * D2n);
        #pragma unroll
        for (int q = 0; q < 5; ++q) {
            const float4 v = wr[q];
            g0[4*q+0] = fmaf(hk0, v.x, g0[4*q+0]);  g1[4*q+0] = fmaf(hk1, v.x, g1[4*q+0]);
            g0[4*q+1] = fmaf(hk0, v.y, g0[4*q+1]);  g1[4*q+1] = fmaf(hk1, v.y, g1[4*q+1]);
            g0[4*q+2] = fmaf(hk0, v.z, g0[4*q+2]);  g1[4*q+2] = fmaf(hk1, v.z, g1[4*q+2]);
            g0[4*q+3] = fmaf(hk0, v.w, g0[4*q+3]);  g1[4*q+3] = fmaf(hk1, v.w, g1[4*q+3]);
        }
    }

    // y = s12 + g . u   (W3/b3 folded)
    float y1_0 = s12[s][0], y1_1 = s12[s][0];
    float y2_0 = s12[s][1], y2_1 = s12[s][1];
    #pragma unroll
    for (int k = 0; k < D2n; ++k) {
        const float gk0 = tanh_fast(g0[k]);
        const float gk1 = tanh_fast(g1[k]);
        const float uk1 = u1l[s][k], uk2 = u2l[s][k];
        y1_0 = fmaf(gk0, uk1, y1_0);  y1_1 = fmaf(gk1, uk1, y1_1);
        y2_0 = fmaf(gk0, uk2, y2_0);  y2_1 = fmaf(gk1, uk2, y2_1);
    }

    const size_t oidx = (size_t)(b0 + s) * En + e0;
    *reinterpret_cast<float2*>(out_y1 + oidx) = make_float2(y1_0, y1_1);
    *reinterpret_cast<float2*>(out_y2 + oidx) = make_float2(y2_0, y2_1);
}

extern "C" void kernel_launch(void* const* d_in, const int* in_sizes, int n_in,
                              void* d_out, int out_size, void* d_ws, size_t ws_size,
                              hipStream_t stream)
{
    const float* x       = (const float*)d_in[0];
    const float* eps     = (const float*)d_in[1];
    const float* alpha   = (const float*)d_in[2];
    const float* centers = (const float*)d_in[3];
    const float* W1      = (const float*)d_in[4];
    const float* b1      = (const float*)d_in[5];
    const float* W2      = (const float*)d_in[6];
    const float* b2      = (const float*)d_in[7];
    const float* W3      = (const float*)d_in[8];
    const float* b3      = (const float*)d_in[9];
    const float* beta_W  = (const float*)d_in[10];
    const float* beta_b  = (const float*)d_in[11];
    const float* eW1     = (const float*)d_in[12];
    const float* eb1     = (const float*)d_in[13];
    const float* eW2     = (const float*)d_in[14];
    const float* eb2     = (const float*)d_in[15];
    const float* Wmu     = (const float*)d_in[16];
    const float* bmu     = (const float*)d_in[17];
    const float* Wlv     = (const float*)d_in[18];
    const float* blv     = (const float*)d_in[19];
    const float* dW1     = (const float*)d_in[20];
    const float* db1     = (const float*)d_in[21];
    const float* dW2     = (const float*)d_in[22];
    const float* db2     = (const float*)d_in[23];
    const float* dW3     = (const float*)d_in[24];
    const float* db3     = (const float*)d_in[25];

    float* out    = (float*)d_out;
    float* out_y1 = out;                                  // (B,E)
    float* out_y2 = out + (size_t)Bn * En;                // (B,E)
    float* out_mu = out + (size_t)2 * Bn * En;            // (B,Z)
    float* out_lv = out_mu + (size_t)Bn * Zn;             // (B,Z)

    pivae_fused3<<<dim3(Bn / 2), dim3(256), 0, stream>>>(
        x, eps, alpha, centers, W1, b1, W2, b2, W3, b3, beta_W, beta_b,
        eW1, eb1, eW2, eb2, Wmu, bmu, Wlv, blv,
        dW1, db1, dW2, db2, dW3, db3,
        out_y1, out_y2, out_mu, out_lv);
}